// Round 3
// baseline (843.043 us; speedup 1.0000x reference)
//
#include <hip/hip_runtime.h>
#include <hip/hip_cooperative_groups.h>
#include <cmath>

namespace cg = cooperative_groups;

#define NSP 1728   // 12*12*12
#define BB  2      // batch
#define SS  12

typedef __attribute__((ext_vector_type(8))) short short8;
typedef __attribute__((ext_vector_type(4))) short short4v;
typedef __attribute__((ext_vector_type(4))) float floatx4;

__device__ __forceinline__ short f2bf(float f) {
    unsigned u = __float_as_uint(f);
    u += 0x7fff + ((u >> 16) & 1);
    return (short)(u >> 16);
}
__device__ __forceinline__ unsigned pack2bf(float a, float b) {
    unsigned ua = __float_as_uint(a); ua += 0x7fff + ((ua >> 16) & 1);
    unsigned ub = __float_as_uint(b); ub += 0x7fff + ((ub >> 16) & 1);
    return (ua >> 16) | (ub & 0xffff0000u);
}
__device__ __forceinline__ short8 ld8(const short* p) {
    short4v a = *(const short4v*)p;
    short4v b = *(const short4v*)(p + 4);
    return __builtin_shufflevector(a, b, 0, 1, 2, 3, 4, 5, 6, 7);
}
__device__ __forceinline__ float fexp2(float x) {
    float r;
    asm("v_exp_f32 %0, %1" : "=v"(r) : "v"(x));
    return r;
}

// ---------------- shared-memory union (one 25.6 KB arena for all phases) ---
union SMemU {
    struct {                       // convm: 25344 B
        float sc[512], sh[512], sa[512], sbl[512], hid[128];
        short xa[16 * 520];        // XP <= 520 (CIN=512)
    } conv;
    struct {                       // indw: ~11 KB
        float tile[14 * 14 * 14];
        float wsh[27];
    } dwc;
    struct {                       // attn: 25600 B
        short kt[288 * 20];
        short vt[16 * 296];
        short pt[4][16 * 36];
    } attn;
    struct {                       // segate
        float pooled[512], hid[128];
    } seg;
    struct {                       // sfinal
        float swl[256];
    } sf;
};

// ---------------- block-wide dual reduction (sum, sumsq) -------------------
__device__ __forceinline__ void block_reduce2(float& s, float& s2) {
    __shared__ float red[8][2];
    __syncthreads();
    #pragma unroll
    for (int o = 32; o; o >>= 1) {
        s  += __shfl_down(s,  o, 64);
        s2 += __shfl_down(s2, o, 64);
    }
    int lane = threadIdx.x & 63, w = threadIdx.x >> 6;
    if (lane == 0) { red[w][0] = s; red[w][1] = s2; }
    __syncthreads();
    int nw = (blockDim.x + 63) >> 6;
    if (threadIdx.x == 0) {
        float a = 0.f, b = 0.f;
        for (int i = 0; i < nw; i++) { a += red[i][0]; b += red[i][1]; }
        red[0][0] = a; red[0][1] = b;
    }
    __syncthreads();
    s = red[0][0]; s2 = red[0][1];
}

// ---------------- params ---------------------------------------------------
struct MegaParams {
    const float *x;
    const float *m1_g1, *m1_b1, *m1_dw, *m1_g2, *m1_b2, *m1_sb1, *m1_sb2, *m1_g3, *m1_b3;
    const float *m2_g1, *m2_b1, *m2_dw, *m2_g2, *m2_b2, *m2_sb1, *m2_sb2, *m2_g3, *m2_b3;
    const float *t_n1g, *t_n1b, *t_pb, *t_n2g, *t_n2b, *t_mb1, *t_mb2;
    const float *s_cw1, *s_cw2, *s_gng, *s_gnb, *s_sw;
    const float *pw0, *pw1, *pw2, *pw3, *pw4, *pw5, *pw6, *pw7;   // conv weight srcs
    const float *sew1a, *sew2a, *sew1b, *sew2b;                   // SE weight srcs
    float *bufA, *bufB, *bufX, *bufY, *bufQKV, *pl;
    float *se_s, *st1, *st3, *st4, *st2, *gate1, *gate2;
    short *wbf;
    float *tsw, *bufX2;
    float *out;
};

// ======= phase 0: weight prep (bf16 convs, SE transposes, zero stats) ======
#define WTOT 376832
__device__ __forceinline__ void prep_dev(int u, const MegaParams& p) {
    if (u < 11) p.st1[u * 256 + threadIdx.x] = 0.f;   // zero 2816-float stats region
    if (u >= 368) {
        int e = (u - 368) * 1024 + threadIdx.x * 4;
        #pragma unroll
        for (int k = 0; k < 4; k++) {
            int idx = e + k;
            float v;
            if (idx < 16384) {
                int c = idx >> 6, r = idx & 63;
                v = p.sew1a[r * 256 + c];
            } else if (idx < 32768) {
                int l = idx - 16384; int r = l >> 8, ci = l & 255;
                v = p.sew2a[ci * 64 + r];
            } else if (idx < 98304) {
                int l = idx - 32768; int c = l >> 7, r = l & 127;
                v = p.sew1b[r * 512 + c];
            } else {
                int l = idx - 98304; int r = l >> 9, ci = l & 511;
                v = p.sew2b[ci * 128 + r];
            }
            p.tsw[idx] = v;
        }
        return;
    }
    const int offs[9] = {0, 16384, 49152, 114688, 180224, 229376, 245760, 311296, WTOT};
    const float* srcs[8] = {p.pw0, p.pw1, p.pw2, p.pw3, p.pw4, p.pw5, p.pw6, p.pw7};
    int e = u * 1024 + threadIdx.x * 4;
    #pragma unroll
    for (int k = 0; k < 4; k++) {
        int idx = e + k;
        int seg = 0;
        while (idx >= offs[seg + 1]) seg++;
        p.wbf[idx] = f2bf(srcs[seg][idx - offs[seg]]);
    }
}

// ======= SE gate (once per batch) ==========================================
template<int CIN, int SER>
__device__ __forceinline__ void segate_dev(SMemU& sm, int b,
        const float* __restrict__ pooled_in,
        const float* __restrict__ w1t, const float* __restrict__ b1,
        const float* __restrict__ w2t, const float* __restrict__ b2,
        float* __restrict__ gate) {
    int tid = threadIdx.x;
    __syncthreads();
    for (int c = tid; c < CIN; c += 256) sm.seg.pooled[c] = pooled_in[b * CIN + c];
    __syncthreads();
    if (tid < SER) {
        float a0 = 0.f, a1 = 0.f, a2 = 0.f, a3 = 0.f;
        for (int c = 0; c < CIN; c += 4) {
            a0 = fmaf(w1t[(size_t)(c + 0) * SER + tid], sm.seg.pooled[c + 0], a0);
            a1 = fmaf(w1t[(size_t)(c + 1) * SER + tid], sm.seg.pooled[c + 1], a1);
            a2 = fmaf(w1t[(size_t)(c + 2) * SER + tid], sm.seg.pooled[c + 2], a2);
            a3 = fmaf(w1t[(size_t)(c + 3) * SER + tid], sm.seg.pooled[c + 3], a3);
        }
        float h = b1[tid] + (a0 + a1) + (a2 + a3);
        sm.seg.hid[tid] = h / (1.f + __expf(-h));
    }
    __syncthreads();
    for (int ci = tid; ci < CIN; ci += 256) {
        float g0 = b2[ci], g1 = 0.f, g2 = 0.f, g3 = 0.f;
        for (int r = 0; r < SER; r += 4) {
            g0 = fmaf(w2t[(size_t)(r + 0) * CIN + ci], sm.seg.hid[r + 0], g0);
            g1 = fmaf(w2t[(size_t)(r + 1) * CIN + ci], sm.seg.hid[r + 1], g1);
            g2 = fmaf(w2t[(size_t)(r + 2) * CIN + ci], sm.seg.hid[r + 2], g2);
            g3 = fmaf(w2t[(size_t)(r + 3) * CIN + ci], sm.seg.hid[r + 3], g3);
        }
        float gv = (g0 + g1) + (g2 + g3);
        gate[b * CIN + ci] = 1.f / (1.f + __expf(-gv));
    }
}

// ======= MFMA 1x1 conv unit ================================================
template<int CIN, int COUT>
__device__ __forceinline__ void convm_dev(SMemU& sm, int flat, int coy,
        const float* __restrict__ in, const short* __restrict__ wb,
        const float* __restrict__ biasc,
        const float* __restrict__ segate,
        const float* __restrict__ fstats, const float* __restrict__ fg,
        const float* __restrict__ fb, int fgs,
        const float* __restrict__ ing, const float* __restrict__ inb,
        const float* __restrict__ inres,
        const float* __restrict__ po, const float* __restrict__ pl,
        float* __restrict__ xout,
        const float* resid, float* out, float* stats_out,
        const float* __restrict__ statres, int act) {
    constexpr int XP = CIN + 8;
    float* sc  = sm.conv.sc;
    float* sh  = sm.conv.sh;
    float* sa  = sm.conv.sa;
    float* sbl = sm.conv.sbl;
    float* hid = sm.conv.hid;
    short* xa  = sm.conv.xa;
    int b = flat / 108, mt = flat % 108;
    int n0 = mt * 16;
    int tid = threadIdx.x;
    __syncthreads();                 // protect LDS reuse across units/phases

    if (po) {
        if (tid < 128) {
            int hh = tid >> 4, j = tid & 15;
            float l = 0.f;
            #pragma unroll
            for (int js = 0; js < 6; js++)
                l += pl[(size_t)((b * 8 + hh) * 6 + js) * NSP + n0 + j];
            hid[tid] = 1.f / l;
        }
        __syncthreads();
        #pragma unroll
        for (int i = 0; i < CIN / 64; i++) {
            int e = tid + i * 256;
            int ci = e >> 2;
            int jj = (e & 3) * 4;
            int hh = ci >> 4, d = ci & 15;
            float4 acc = {0.f, 0.f, 0.f, 0.f};
            #pragma unroll
            for (int js = 0; js < 6; js++) {
                float4 pv = *(const float4*)(po +
                    ((size_t)((b * 8 + hh) * 6 + js) * 16 + d) * NSP + n0 + jj);
                acc.x += pv.x; acc.y += pv.y; acc.z += pv.z; acc.w += pv.w;
            }
            float4 li = *(const float4*)(hid + hh * 16 + jj);
            xa[(jj + 0) * XP + ci] = f2bf(acc.x * li.x);
            xa[(jj + 1) * XP + ci] = f2bf(acc.y * li.y);
            xa[(jj + 2) * XP + ci] = f2bf(acc.z * li.z);
            xa[(jj + 3) * XP + ci] = f2bf(acc.w * li.w);
        }
        __syncthreads();
    } else {
        if (segate) {
            for (int c = tid; c < CIN; c += 256) {
                sc[c] = segate[b * CIN + c];
                sh[c] = 0.f;
            }
        } else if (ing) {
            for (int c = tid; c < CIN; c += 256) {
                const float* S = fstats + (size_t)(b * CIN + c) * 5;
                float A = S[0], Bq = S[1], Cq = S[2], Dq = S[3], Eq = S[4];
                const float N = (float)NSP;
                float mean = A / N, var = Bq / N - mean * mean;
                float a_ = ing[c] * rsqrtf(var + 1e-5f);
                float b_ = inb[c] - mean * a_;
                sa[c] = a_; sbl[c] = b_;
                sc[c] = a_ * A + b_ * N + Dq;
                sh[c] = a_ * a_ * Bq + 2.f * a_ * b_ * A + b_ * b_ * N
                      + 2.f * a_ * Cq + 2.f * b_ * Dq + Eq;
            }
            __syncthreads();
            float gS = 0.f, gS2 = 0.f;
            if (tid < CIN) {
                int g0 = (tid / fgs) * fgs;
                for (int k = 0; k < fgs; k++) { gS += sc[g0 + k]; gS2 += sh[g0 + k]; }
            }
            __syncthreads();
            if (tid < CIN) {
                float Ng = fgs * (float)NSP;
                float gm = gS / Ng, gv = gS2 / Ng - gm * gm;
                float s_ = rsqrtf(gv + 1e-5f) * fg[tid];
                sc[tid] = s_;
                sh[tid] = fb[tid] - gm * s_;
            }
        } else if (fstats) {
            for (int c = tid; c < CIN; c += 256) {
                int g0 = c / fgs;
                float S = 0.f, S2 = 0.f;
                for (int k = 0; k < fgs; k++) {
                    S  += fstats[(b * CIN + g0 * fgs + k) * 2];
                    S2 += fstats[(b * CIN + g0 * fgs + k) * 2 + 1];
                }
                float N = fgs * (float)NSP;
                float mean = S / N, var = S2 / N - mean * mean;
                float s = rsqrtf(var + 1e-5f) * fg[c];
                sc[c] = s;
                sh[c] = fb[c] - mean * s;
            }
        } else {
            for (int c = tid; c < CIN; c += 256) { sc[c] = 1.f; sh[c] = 0.f; }
        }
        __syncthreads();

        bool dosw = (xout != nullptr) && (coy == 0);
        #pragma unroll
        for (int i = 0; i < CIN / 64; i++) {
            int e = tid + i * 256;
            int ci = e >> 2;
            int jj = (e & 3) * 4;
            size_t gi = ((size_t)b * CIN + ci) * NSP + n0 + jj;
            float4 v4 = *(const float4*)(in + gi);
            float v0, v1, v2, v3;
            if (ing) {
                float4 rr = *(const float4*)(inres + gi);
                float a_ = sa[ci], b_ = sbl[ci];
                float x0 = fmaf(v4.x, a_, b_) + rr.x;
                float x1 = fmaf(v4.y, a_, b_) + rr.y;
                float x2 = fmaf(v4.z, a_, b_) + rr.z;
                float x3 = fmaf(v4.w, a_, b_) + rr.w;
                if (dosw) {
                    float4 o; o.x = x0; o.y = x1; o.z = x2; o.w = x3;
                    *(float4*)(xout + gi) = o;
                }
                float s_ = sc[ci], h_ = sh[ci];
                v0 = fmaf(x0, s_, h_); v1 = fmaf(x1, s_, h_);
                v2 = fmaf(x2, s_, h_); v3 = fmaf(x3, s_, h_);
            } else {
                float s_ = sc[ci], h_ = sh[ci];
                v0 = fmaf(v4.x, s_, h_); v1 = fmaf(v4.y, s_, h_);
                v2 = fmaf(v4.z, s_, h_); v3 = fmaf(v4.w, s_, h_);
                if (dosw) {
                    float4 o; o.x = v0; o.y = v1; o.z = v2; o.w = v3;
                    *(float4*)(xout + gi) = o;
                }
            }
            xa[(jj + 0) * XP + ci] = f2bf(v0);
            xa[(jj + 1) * XP + ci] = f2bf(v1);
            xa[(jj + 2) * XP + ci] = f2bf(v2);
            xa[(jj + 3) * XP + ci] = f2bf(v3);
        }
        __syncthreads();
    }

    int lane = tid & 63, wv = tid >> 6;
    int col = lane & 15, quad = lane >> 4;
    short8 afr[CIN / 32];
    #pragma unroll
    for (int kc = 0; kc < CIN / 32; kc++)
        afr[kc] = ld8(xa + col * XP + kc * 32 + quad * 8);

    int cobase = coy * 64 + wv * 16;
    int co = cobase + col;
    const short* wrow = wb + (size_t)co * CIN;
    floatx4 acc = {0.f, 0.f, 0.f, 0.f};
    #pragma unroll
    for (int kc = 0; kc < CIN / 32; kc++) {
        short8 bw = ld8(wrow + kc * 32 + quad * 8);
        acc = __builtin_amdgcn_mfma_f32_16x16x32_bf16(afr[kc], bw, acc, 0, 0, 0);
    }
    float bv = biasc ? biasc[co] : 0.f;
    float r0 = acc[0] + bv, r1 = acc[1] + bv, r2 = acc[2] + bv, r3 = acc[3] + bv;
    if (act == 2) {
        r0 = 0.5f * r0 * (1.f + erff(r0 * 0.70710678118654752f));
        r1 = 0.5f * r1 * (1.f + erff(r1 * 0.70710678118654752f));
        r2 = 0.5f * r2 * (1.f + erff(r2 * 0.70710678118654752f));
        r3 = 0.5f * r3 * (1.f + erff(r3 * 0.70710678118654752f));
    }
    size_t oi = ((size_t)b * COUT + co) * NSP + n0 + quad * 4;
    if (resid) {
        float4 rv = *(const float4*)(resid + oi);
        r0 += rv.x; r1 += rv.y; r2 += rv.z; r3 += rv.w;
    }
    float4 ov; ov.x = r0; ov.y = r1; ov.z = r2; ov.w = r3;
    *(float4*)(out + oi) = ov;
    if (stats_out) {
        if (statres) {
            float4 rv = *(const float4*)(statres + oi);
            float s   = (r0 + r1) + (r2 + r3);
            float s2  = (r0 * r0 + r1 * r1) + (r2 * r2 + r3 * r3);
            float sx  = (r0 * rv.x + r1 * rv.y) + (r2 * rv.z + r3 * rv.w);
            float sr  = (rv.x + rv.y) + (rv.z + rv.w);
            float sr2 = (rv.x * rv.x + rv.y * rv.y) + (rv.z * rv.z + rv.w * rv.w);
            s   += __shfl_xor(s,   16, 64); s   += __shfl_xor(s,   32, 64);
            s2  += __shfl_xor(s2,  16, 64); s2  += __shfl_xor(s2,  32, 64);
            sx  += __shfl_xor(sx,  16, 64); sx  += __shfl_xor(sx,  32, 64);
            sr  += __shfl_xor(sr,  16, 64); sr  += __shfl_xor(sr,  32, 64);
            sr2 += __shfl_xor(sr2, 16, 64); sr2 += __shfl_xor(sr2, 32, 64);
            if (lane < 16) {
                float* sp = stats_out + (size_t)(b * COUT + cobase + lane) * 5;
                atomicAdd(sp + 0, s);
                atomicAdd(sp + 1, s2);
                atomicAdd(sp + 2, sx);
                atomicAdd(sp + 3, sr);
                atomicAdd(sp + 4, sr2);
            }
        } else {
            float s  = (r0 + r1) + (r2 + r3);
            float s2 = (r0 * r0 + r1 * r1) + (r2 * r2 + r3 * r3);
            s  += __shfl_xor(s,  16, 64);
            s  += __shfl_xor(s,  32, 64);
            s2 += __shfl_xor(s2, 16, 64);
            s2 += __shfl_xor(s2, 32, 64);
            if (lane < 16) {
                atomicAdd(&stats_out[(b * COUT + cobase + lane) * 2],     s);
                atomicAdd(&stats_out[(b * COUT + cobase + lane) * 2 + 1], s2);
            }
        }
    }
}

// ======= IN+SiLU + depthwise 3x3x3 + IN+SiLU + SE-squeeze unit =============
__device__ __forceinline__ void indw_dev(SMemU& sm, int bc,
        const float* __restrict__ in,
        const float* __restrict__ g1, const float* __restrict__ b1,
        const float* __restrict__ dw,
        const float* __restrict__ g2, const float* __restrict__ b2,
        float* __restrict__ out, float* __restrict__ se_s, int C) {
    int c = bc % C;
    float* tile = sm.dwc.tile;
    float* wsh  = sm.dwc.wsh;
    __syncthreads();
    const float* ip = in + (size_t)bc * NSP;
    float r[7];
    float s = 0.f, s2 = 0.f;
    for (int i = threadIdx.x; i < 2744; i += 256) tile[i] = 0.f;
    #pragma unroll
    for (int i = 0; i < 7; i++) {
        int n = threadIdx.x + i * 256;
        if (n < NSP) { r[i] = ip[n]; s += r[i]; s2 += r[i] * r[i]; }
        else r[i] = 0.f;
    }
    if (threadIdx.x < 27) wsh[threadIdx.x] = dw[(size_t)c * 27 + threadIdx.x];
    block_reduce2(s, s2);
    float mean = s / NSP, var = s2 / NSP - (s / NSP) * (s / NSP);
    float rstd = rsqrtf(var + 1e-5f);
    float gc = g1[c], bc1 = b1[c];
    #pragma unroll
    for (int i = 0; i < 7; i++) {
        int n = threadIdx.x + i * 256;
        if (n < NSP) {
            int z = n / 144, y = (n / 12) % 12, x = n % 12;
            float v = (r[i] - mean) * rstd * gc + bc1;
            tile[((z + 1) * 14 + y + 1) * 14 + x + 1] = v / (1.f + __expf(-v));
        }
    }
    __syncthreads();
    float d[7];
    #pragma unroll
    for (int i = 0; i < 7; i++) {
        int n = threadIdx.x + i * 256;
        d[i] = 0.f;
        if (n < NSP) {
            int z = n / 144, y = (n / 12) % 12, x = n % 12;
            const float* ctr = tile + ((z + 1) * 14 + y + 1) * 14 + x + 1;
            float acc = 0.f;
            #pragma unroll
            for (int dz = 0; dz < 3; dz++)
                #pragma unroll
                for (int dy = 0; dy < 3; dy++)
                    #pragma unroll
                    for (int dx = 0; dx < 3; dx++)
                        acc = fmaf(wsh[dz * 9 + dy * 3 + dx],
                                   ctr[(dz - 1) * 196 + (dy - 1) * 14 + (dx - 1)], acc);
            d[i] = acc;
        }
    }
    s = 0.f; s2 = 0.f;
    #pragma unroll
    for (int i = 0; i < 7; i++) {
        int n = threadIdx.x + i * 256;
        if (n < NSP) { s += d[i]; s2 += d[i] * d[i]; }
    }
    block_reduce2(s, s2);
    mean = s / NSP; var = s2 / NSP - mean * mean;
    rstd = rsqrtf(var + 1e-5f);
    float gc2 = g2[c], bc2 = b2[c];
    float ssum = 0.f;
    float* op = out + (size_t)bc * NSP;
    #pragma unroll
    for (int i = 0; i < 7; i++) {
        int n = threadIdx.x + i * 256;
        if (n < NSP) {
            float v = (d[i] - mean) * rstd * gc2 + bc2;
            v = v / (1.f + __expf(-v));
            op[n] = v;
            ssum += v;
        }
    }
    float dummy = 0.f;
    block_reduce2(ssum, dummy);
    if (threadIdx.x == 0) se_s[bc] = ssum / NSP;
}

// ======= flash attention unit ==============================================
#define AKT 20
#define AVT 296
#define APT 36
#define JCH 288
__device__ __forceinline__ void attn_dev(SMemU& sm, int bh, int qy, int js,
        const float* __restrict__ qkv, float* __restrict__ po,
        float* __restrict__ pl) {
    short* kt = sm.attn.kt;
    short* vt = sm.attn.vt;
    __syncthreads();
    int b = bh >> 3, h = bh & 7;
    int j0 = js * JCH;
    const float* base = qkv + (size_t)b * 384 * NSP;
    const float* qp = base + (size_t)(h * 16) * NSP;
    const float* kp = base + (size_t)(128 + h * 16) * NSP;
    const float* vp = base + (size_t)(256 + h * 16) * NSP;
    for (int t = threadIdx.x; t < 16 * 144; t += 256) {
        int d = t / 144, j = (t - d * 144) * 2;
        float2 kv2 = *(const float2*)(kp + (size_t)d * NSP + j0 + j);
        float2 vv2 = *(const float2*)(vp + (size_t)d * NSP + j0 + j);
        kt[j * AKT + d]       = f2bf(kv2.x);
        kt[(j + 1) * AKT + d] = f2bf(kv2.y);
        *(unsigned*)(vt + d * AVT + j) = pack2bf(vv2.x, vv2.y);
    }
    int wave = threadIdx.x >> 6, lane = threadIdx.x & 63;
    int m = lane & 15, quad = lane >> 4;
    int q0 = (qy * 4 + wave) * 16;
    short* ptw = sm.attn.pt[wave];
    short8 qa;
    #pragma unroll
    for (int i = 0; i < 8; i++) qa[i] = 0;
    if (quad < 2) {
        #pragma unroll
        for (int i = 0; i < 8; i++) {
            int d = quad * 8 + i;
            qa[i] = f2bf(qp[(size_t)d * NSP + q0 + m] * 0.36067376022224085f);
        }
    }
    __syncthreads();
    floatx4 o = {0.f, 0.f, 0.f, 0.f};
    float ls = 0.f;
    for (int s = 0; s < 9; s++) {
        int jl = s * 32;
        short8 ak0, ak1;
        #pragma unroll
        for (int i = 0; i < 8; i++) { ak0[i] = 0; ak1[i] = 0; }
        if (quad < 2) {
            ak0 = ld8(kt + (jl + m) * AKT + quad * 8);
            ak1 = ld8(kt + (jl + 16 + m) * AKT + quad * 8);
        }
        floatx4 s0 = {0.f, 0.f, 0.f, 0.f}, s1 = {0.f, 0.f, 0.f, 0.f};
        s0 = __builtin_amdgcn_mfma_f32_16x16x32_bf16(ak0, qa, s0, 0, 0, 0);
        s1 = __builtin_amdgcn_mfma_f32_16x16x32_bf16(ak1, qa, s1, 0, 0, 0);
        float p0r0 = fexp2(s0[0]), p0r1 = fexp2(s0[1]), p0r2 = fexp2(s0[2]), p0r3 = fexp2(s0[3]);
        float p1r0 = fexp2(s1[0]), p1r1 = fexp2(s1[1]), p1r2 = fexp2(s1[2]), p1r3 = fexp2(s1[3]);
        ls += (p0r0 + p0r1) + (p0r2 + p0r3) + (p1r0 + p1r1) + (p1r2 + p1r3);
        uint2 w0, w1;
        w0.x = pack2bf(p0r0, p0r1); w0.y = pack2bf(p0r2, p0r3);
        w1.x = pack2bf(p1r0, p1r1); w1.y = pack2bf(p1r2, p1r3);
        *(uint2*)(ptw + m * APT + quad * 4)      = w0;
        *(uint2*)(ptw + m * APT + 16 + quad * 4) = w1;
        short8 av = ld8(vt + m * AVT + jl + quad * 8);
        short8 pb = ld8(ptw + m * APT + quad * 8);
        o = __builtin_amdgcn_mfma_f32_16x16x32_bf16(av, pb, o, 0, 0, 0);
    }
    ls += __shfl_xor(ls, 16, 64);
    ls += __shfl_xor(ls, 32, 64);
    size_t pbase = ((size_t)(bh * 6 + js) * 16) * NSP;
    #pragma unroll
    for (int r = 0; r < 4; r++)
        po[pbase + (size_t)(quad * 4 + r) * NSP + q0 + m] = o[r];
    if (quad == 0) pl[(size_t)(bh * 6 + js) * NSP + q0 + m] = ls;
}

// ======= shuffle attn final unit (256 threads, u = bg + 8*chunk) ===========
__device__ __forceinline__ void sfinal_dev(SMemU& sm, int u,
        const float* __restrict__ X, const float* __restrict__ st,
        const float* __restrict__ cw1, const float* __restrict__ cw2,
        const float* __restrict__ gng, const float* __restrict__ gnb,
        const float* __restrict__ sw, float* __restrict__ out) {
    int bg = u & 7;
    int n = (u >> 3) * 256 + threadIdx.x;
    int b = bg >> 2, g = bg & 3;
    float* swl = sm.sf.swl;
    __syncthreads();
    swl[threadIdx.x] = sw[threadIdx.x];
    __syncthreads();
    if (n >= NSP) return;   // no further __syncthreads in this unit
    float pooled[16];
    #pragma unroll
    for (int j = 0; j < 16; j++)
        pooled[j] = st[(b * 128 + g * 32 + j) * 2] * (1.f / NSP);
    float hid[4];
    #pragma unroll
    for (int r = 0; r < 4; r++) {
        float a = 0.f;
        #pragma unroll
        for (int j = 0; j < 16; j++) a = fmaf(cw1[r * 16 + j], pooled[j], a);
        hid[r] = a / (1.f + __expf(-a));
    }
    float gate[16];
    #pragma unroll
    for (int j = 0; j < 16; j++) {
        float a = 0.f;
        #pragma unroll
        for (int r = 0; r < 4; r++) a = fmaf(cw2[j * 4 + r], hid[r], a);
        gate[j] = 1.f / (1.f + __expf(-a));
    }
    float gmean[2], grstd[2];
    #pragma unroll
    for (int t = 0; t < 2; t++) {
        float S = 0.f, S2 = 0.f;
        #pragma unroll
        for (int k = 0; k < 8; k++) {
            int c = g * 32 + 16 + t * 8 + k;
            S  += st[(b * 128 + c) * 2];
            S2 += st[(b * 128 + c) * 2 + 1];
        }
        float N = 8.f * NSP;
        gmean[t] = S / N;
        grstd[t] = rsqrtf(S2 / N - gmean[t] * gmean[t] + 1e-5f);
    }
    const float* xb = X + (size_t)b * 128 * NSP;
    #pragma unroll
    for (int j = 0; j < 16; j++) {
        float v = xb[(size_t)(g * 32 + j) * NSP + n] * gate[j];
        int k = g * 16 + j;
        int cp = (k % 32) * 4 + (k / 32);
        out[((size_t)b * 128 + cp) * NSP + n] = v;
    }
    float sgn[16];
    #pragma unroll
    for (int j = 0; j < 16; j++) {
        int grp = j >> 3;
        float xv = xb[(size_t)(g * 32 + 16 + j) * NSP + n];
        sgn[j] = (xv - gmean[grp]) * grstd[grp] * gng[j] + gnb[j];
    }
    #pragma unroll
    for (int j = 0; j < 16; j++) {
        float a = 0.f;
        #pragma unroll
        for (int jp = 0; jp < 16; jp++) a = fmaf(swl[j * 16 + jp], sgn[jp], a);
        float v = (1.f / (1.f + __expf(-a))) * xb[(size_t)(g * 32 + 16 + j) * NSP + n];
        int k = 64 + g * 16 + j;
        int cp = (k % 32) * 4 + (k / 32);
        out[((size_t)b * 128 + cp) * NSP + n] = v;
    }
}

// ======= THE persistent cooperative kernel =================================
__global__ __launch_bounds__(256, 2) void mega_kernel(MegaParams p) {
    __shared__ __align__(16) SMemU sm;
    cg::grid_group gg = cg::this_grid();
    const int NB = gridDim.x;
    const int bid = blockIdx.x;

    // P0: weight prep
    for (int u = bid; u < 528; u += NB) prep_dev(u, p);
    gg.sync();

    // P1: MBConv1 expand 64->256
    for (int u = bid; u < 216 * 4; u += NB)
        convm_dev<64, 256>(sm, u % 216, u / 216,
            p.x, p.wbf + 0, nullptr, nullptr,
            nullptr, nullptr, nullptr, 0,
            nullptr, nullptr, nullptr,
            nullptr, nullptr, nullptr,
            nullptr, p.bufA, nullptr, nullptr, 0);
    gg.sync();

    // P2: indw C=256
    for (int u = bid; u < BB * 256; u += NB)
        indw_dev(sm, u, p.bufA, p.m1_g1, p.m1_b1, p.m1_dw, p.m1_g2, p.m1_b2,
                 p.bufB, p.se_s, 256);
    gg.sync();

    // P3: segate1
    for (int u = bid; u < BB; u += NB)
        segate_dev<256, 64>(sm, u, p.se_s, p.tsw, p.m1_sb1,
                            p.tsw + 16384, p.m1_sb2, p.gate1);
    gg.sync();

    // P4: MBConv1 proj 256->128 (+SE gate, 2-term stats)
    for (int u = bid; u < 216 * 2; u += NB)
        convm_dev<256, 128>(sm, u % 216, u / 216,
            p.bufB, p.wbf + 16384, nullptr, p.gate1,
            nullptr, nullptr, nullptr, 0,
            nullptr, nullptr, nullptr,
            nullptr, nullptr, nullptr,
            nullptr, p.bufY, p.st1, nullptr, 0);
    gg.sync();

    // P5: MBConv2 expand 128->512 (IN-fold, side-write x1)
    for (int u = bid; u < 216 * 8; u += NB)
        convm_dev<128, 512>(sm, u % 216, u / 216,
            p.bufY, p.wbf + 49152, nullptr, nullptr,
            p.st1, p.m1_g3, p.m1_b3, 1,
            nullptr, nullptr, nullptr,
            nullptr, nullptr, p.bufX,
            nullptr, p.bufA, nullptr, nullptr, 0);
    gg.sync();

    // P6: indw C=512
    for (int u = bid; u < BB * 512; u += NB)
        indw_dev(sm, u, p.bufA, p.m2_g1, p.m2_b1, p.m2_dw, p.m2_g2, p.m2_b2,
                 p.bufB, p.se_s, 512);
    gg.sync();

    // P7: segate2
    for (int u = bid; u < BB; u += NB)
        segate_dev<512, 128>(sm, u, p.se_s, p.tsw + 32768, p.m2_sb1,
                             p.tsw + 98304, p.m2_sb2, p.gate2);
    gg.sync();

    // P8: MBConv2 proj 512->128 (+SE gate, 5-term stats vs x1)
    for (int u = bid; u < 216 * 2; u += NB)
        convm_dev<512, 128>(sm, u % 216, u / 216,
            p.bufB, p.wbf + 114688, nullptr, p.gate2,
            nullptr, nullptr, nullptr, 0,
            nullptr, nullptr, nullptr,
            nullptr, nullptr, nullptr,
            nullptr, p.bufY, p.st2, p.bufX, 0);
    gg.sync();

    // P9: qkv 128->384 (IN+resid closed-form + gnorm1-fold, side-write x2)
    for (int u = bid; u < 216 * 6; u += NB)
        convm_dev<128, 384>(sm, u % 216, u / 216,
            p.bufY, p.wbf + 180224, nullptr, nullptr,
            p.st2, p.t_n1g, p.t_n1b, 4,
            p.m2_g3, p.m2_b3, p.bufX,
            nullptr, nullptr, p.bufX2,
            nullptr, p.bufQKV, nullptr, nullptr, 0);
    gg.sync();

    // P10: attention (16 bh x 27 qy x 6 js)
    for (int u = bid; u < 16 * 27 * 6; u += NB) {
        int bh = u % 16, qy = (u / 16) % 27, js = u / (16 * 27);
        attn_dev(sm, bh, qy, js, p.bufQKV, p.bufA, p.pl);
    }
    gg.sync();

    // P11: attn merge + proj 128->128 (+resid, 2-term stats)
    for (int u = bid; u < 216 * 2; u += NB)
        convm_dev<128, 128>(sm, u % 216, u / 216,
            nullptr, p.wbf + 229376, p.t_pb, nullptr,
            nullptr, nullptr, nullptr, 0,
            nullptr, nullptr, nullptr,
            p.bufA, p.pl, nullptr,
            p.bufX2, p.bufX2, p.st3, nullptr, 0);
    gg.sync();

    // P12: mlp1 128->512 (gnorm2-fold + GELU)
    for (int u = bid; u < 216 * 8; u += NB)
        convm_dev<128, 512>(sm, u % 216, u / 216,
            p.bufX2, p.wbf + 245760, p.t_mb1, nullptr,
            p.st3, p.t_n2g, p.t_n2b, 4,
            nullptr, nullptr, nullptr,
            nullptr, nullptr, nullptr,
            nullptr, p.bufA, nullptr, nullptr, 2);
    gg.sync();

    // P13: mlp2 512->128 (+resid, 2-term stats)
    for (int u = bid; u < 216 * 2; u += NB)
        convm_dev<512, 128>(sm, u % 216, u / 216,
            p.bufA, p.wbf + 311296, p.t_mb2, nullptr,
            nullptr, nullptr, nullptr, 0,
            nullptr, nullptr, nullptr,
            nullptr, nullptr, nullptr,
            p.bufX2, p.bufX2, p.st4, nullptr, 0);
    gg.sync();

    // P14: shuffle-attn final (56 units: 8 bg x 7 n-chunks)
    for (int u = bid; u < 56; u += NB)
        sfinal_dev(sm, u, p.bufX2, p.st4, p.s_cw1, p.s_cw2,
                   p.s_gng, p.s_gnb, p.s_sw, p.out);
}

// ===========================================================================
extern "C" void kernel_launch(void* const* d_in, const int* in_sizes, int n_in,
                              void* d_out, int out_size, void* d_ws, size_t ws_size,
                              hipStream_t stream) {
    MegaParams mp;
    mp.x      = (const float*)d_in[0];
    const float* m1_ew = (const float*)d_in[1];
    mp.m1_g1  = (const float*)d_in[2];
    mp.m1_b1  = (const float*)d_in[3];
    mp.m1_dw  = (const float*)d_in[4];
    mp.m1_g2  = (const float*)d_in[5];
    mp.m1_b2  = (const float*)d_in[6];
    mp.sew1a  = (const float*)d_in[7];    // m1_sw1
    mp.m1_sb1 = (const float*)d_in[8];
    mp.sew2a  = (const float*)d_in[9];    // m1_sw2
    mp.m1_sb2 = (const float*)d_in[10];
    const float* m1_pw = (const float*)d_in[11];
    mp.m1_g3  = (const float*)d_in[12];
    mp.m1_b3  = (const float*)d_in[13];
    const float* m2_ew = (const float*)d_in[14];
    mp.m2_g1  = (const float*)d_in[15];
    mp.m2_b1  = (const float*)d_in[16];
    mp.m2_dw  = (const float*)d_in[17];
    mp.m2_g2  = (const float*)d_in[18];
    mp.m2_b2  = (const float*)d_in[19];
    mp.sew1b  = (const float*)d_in[20];   // m2_sw1
    mp.m2_sb1 = (const float*)d_in[21];
    mp.sew2b  = (const float*)d_in[22];   // m2_sw2
    mp.m2_sb2 = (const float*)d_in[23];
    const float* m2_pw = (const float*)d_in[24];
    mp.m2_g3  = (const float*)d_in[25];
    mp.m2_b3  = (const float*)d_in[26];
    mp.t_n1g  = (const float*)d_in[27];
    mp.t_n1b  = (const float*)d_in[28];
    const float* t_qkv = (const float*)d_in[29];
    const float* t_pw  = (const float*)d_in[30];
    mp.t_pb   = (const float*)d_in[31];
    mp.t_n2g  = (const float*)d_in[32];
    mp.t_n2b  = (const float*)d_in[33];
    const float* t_mw1 = (const float*)d_in[34];
    mp.t_mb1  = (const float*)d_in[35];
    const float* t_mw2 = (const float*)d_in[36];
    mp.t_mb2  = (const float*)d_in[37];
    mp.s_cw1  = (const float*)d_in[38];
    mp.s_cw2  = (const float*)d_in[39];
    mp.s_gng  = (const float*)d_in[40];
    mp.s_gnb  = (const float*)d_in[41];
    mp.s_sw   = (const float*)d_in[42];

    mp.pw0 = m1_ew; mp.pw1 = m1_pw; mp.pw2 = m2_ew; mp.pw3 = m2_pw;
    mp.pw4 = t_qkv; mp.pw5 = t_pw;  mp.pw6 = t_mw1; mp.pw7 = t_mw2;

    mp.out = (float*)d_out;

    float* ws = (float*)d_ws;
    mp.bufA   = ws;                                     // 2*512*NSP (also attn po)
    mp.bufB   = mp.bufA + (size_t)BB * 512 * NSP;       // 2*512*NSP
    mp.bufX   = mp.bufB + (size_t)BB * 512 * NSP;       // 2*128*NSP (x1)
    mp.bufY   = mp.bufX + (size_t)BB * 128 * NSP;       // 2*128*NSP (raw proj out)
    mp.bufQKV = mp.bufY + (size_t)BB * 128 * NSP;       // 2*384*NSP
    mp.pl     = mp.bufQKV + (size_t)BB * 384 * NSP;     // 16*6*NSP
    float* small = mp.pl + (size_t)16 * 6 * NSP;
    mp.se_s   = small;            // 1024 (pooled means from indw)
    mp.st1    = small + 1024;     // 512  (zeroed by prep, atomic)
    mp.st3    = small + 1536;     // 512
    mp.st4    = small + 2048;     // 512
    mp.st2    = small + 2560;     // 1280 (5-term)
    mp.gate1  = small + 4096;     // 512
    mp.gate2  = small + 4608;     // 1024
    mp.wbf    = (short*)(small + 8192);   // 376832 bf16 weights
    mp.tsw    = small + 196608;   // 163840 fp32 transposed SE weights
    mp.bufX2  = mp.tsw + 163840;  // 2*128*NSP (x2 materialized)

    // grid: clamp to guaranteed co-residency (cooperative requirement)
    static int s_nblk = 0;
    if (s_nblk == 0) {
        int dev = 0;
        hipGetDevice(&dev);
        hipDeviceProp_t prop;
        hipGetDeviceProperties(&prop, dev);
        int occ = 0;
        hipOccupancyMaxActiveBlocksPerMultiprocessor(&occ, mega_kernel, 256, 0);
        if (occ < 1) occ = 1;
        long cap = (long)occ * prop.multiProcessorCount;
        if (cap > 1024) cap = 1024;
        if (cap < 1) cap = 1;
        s_nblk = (int)cap;
    }

    void* args[] = {&mp};
    hipLaunchCooperativeKernel(mega_kernel, dim3(s_nblk), dim3(256),
                               args, 0, stream);
}

// Round 4
// 314.013 us; speedup vs baseline: 2.6847x; 2.6847x over previous
//
#include <hip/hip_runtime.h>
#include <cmath>

#define NSP 1728   // 12*12*12
#define BB  2      // batch
#define SS  12

typedef __attribute__((ext_vector_type(8))) short short8;
typedef __attribute__((ext_vector_type(4))) short short4v;
typedef __attribute__((ext_vector_type(4))) float floatx4;

__device__ __forceinline__ short f2bf(float f) {
    unsigned u = __float_as_uint(f);
    u += 0x7fff + ((u >> 16) & 1);
    return (short)(u >> 16);
}
__device__ __forceinline__ unsigned pack2bf(float a, float b) {
    unsigned ua = __float_as_uint(a); ua += 0x7fff + ((ua >> 16) & 1);
    unsigned ub = __float_as_uint(b); ub += 0x7fff + ((ub >> 16) & 1);
    return (ua >> 16) | (ub & 0xffff0000u);
}
__device__ __forceinline__ short8 ld8(const short* p) {
    short4v a = *(const short4v*)p;
    short4v b = *(const short4v*)(p + 4);
    return __builtin_shufflevector(a, b, 0, 1, 2, 3, 4, 5, 6, 7);
}
// raw hardware exp2 (1 inst; inputs here are O(±3), far from edge cases)
__device__ __forceinline__ float fexp2(float x) {
    float r;
    asm("v_exp_f32 %0, %1" : "=v"(r) : "v"(x));
    return r;
}

// ---------------- block-wide dual reduction (sum, sumsq) -------------------
__device__ __forceinline__ void block_reduce2(float& s, float& s2) {
    __shared__ float red[8][2];
    __syncthreads();
    #pragma unroll
    for (int o = 32; o; o >>= 1) {
        s  += __shfl_down(s,  o, 64);
        s2 += __shfl_down(s2, o, 64);
    }
    int lane = threadIdx.x & 63, w = threadIdx.x >> 6;
    if (lane == 0) { red[w][0] = s; red[w][1] = s2; }
    __syncthreads();
    int nw = (blockDim.x + 63) >> 6;
    if (threadIdx.x == 0) {
        float a = 0.f, b = 0.f;
        for (int i = 0; i < nw; i++) { a += red[i][0]; b += red[i][1]; }
        red[0][0] = a; red[0][1] = b;
    }
    __syncthreads();
    s = red[0][0]; s2 = red[0][1];
}

// ======= weight prep: fp32 -> bf16 convs + fp32 SE-weight transposes =======
#define WTOT 376832
__global__ __launch_bounds__(256) void prep_kernel(
        const float* __restrict__ s0, const float* __restrict__ s1,
        const float* __restrict__ s2, const float* __restrict__ s3,
        const float* __restrict__ s4, const float* __restrict__ s5,
        const float* __restrict__ s6, const float* __restrict__ s7,
        short* __restrict__ dst, float* __restrict__ stz,
        const float* __restrict__ w1a, const float* __restrict__ w2a,
        const float* __restrict__ w1b, const float* __restrict__ w2b,
        float* __restrict__ tsw) {
    if (blockIdx.x < 11) stz[blockIdx.x * 256 + threadIdx.x] = 0.f;
    if (blockIdx.x >= 368) {
        int e = (blockIdx.x - 368) * 1024 + threadIdx.x * 4;
        #pragma unroll
        for (int k = 0; k < 4; k++) {
            int idx = e + k;
            float v;
            if (idx < 16384) {
                int c = idx >> 6, r = idx & 63;
                v = w1a[r * 256 + c];
            } else if (idx < 32768) {
                int l = idx - 16384; int r = l >> 8, ci = l & 255;
                v = w2a[ci * 64 + r];
            } else if (idx < 98304) {
                int l = idx - 32768; int c = l >> 7, r = l & 127;
                v = w1b[r * 512 + c];
            } else {
                int l = idx - 98304; int r = l >> 9, ci = l & 511;
                v = w2b[ci * 128 + r];
            }
            tsw[idx] = v;
        }
        return;
    }
    const int offs[9] = {0, 16384, 49152, 114688, 180224, 229376, 245760, 311296, WTOT};
    const float* srcs[8] = {s0, s1, s2, s3, s4, s5, s6, s7};
    int e = blockIdx.x * 1024 + threadIdx.x * 4;
    #pragma unroll
    for (int k = 0; k < 4; k++) {
        int idx = e + k;
        int seg = 0;
        while (idx >= offs[seg + 1]) seg++;
        dst[idx] = f2bf(srcs[seg][idx - offs[seg]]);
    }
}

// ======= SE gate: computed ONCE per batch ==================================
template<int CIN, int SER>
__global__ __launch_bounds__(1024) void segate_kernel(
        const float* __restrict__ pooled_in,
        const float* __restrict__ w1t, const float* __restrict__ b1,
        const float* __restrict__ w2t, const float* __restrict__ b2,
        float* __restrict__ gate) {
    __shared__ float pooled[CIN];
    __shared__ float hid[SER];
    __shared__ float part[1024];
    int b = blockIdx.x;
    int tid = threadIdx.x;
    if (tid < CIN) pooled[tid] = pooled_in[b * CIN + tid];
    __syncthreads();
    {
        constexpr int S = 1024 / SER;
        constexpr int CC = CIN / S;
        int r = tid % SER, s = tid / SER;
        const float* wp = w1t + (size_t)(s * CC) * SER + r;
        float a = 0.f;
        #pragma unroll 4
        for (int c = 0; c < CC; c++) a = fmaf(wp[(size_t)c * SER], pooled[s * CC + c], a);
        part[tid] = a;
    }
    __syncthreads();
    if (tid < SER) {
        constexpr int S = 1024 / SER;
        float h = b1[tid];
        #pragma unroll
        for (int s2 = 0; s2 < S; s2++) h += part[s2 * SER + tid];
        hid[tid] = h / (1.f + __expf(-h));
    }
    __syncthreads();
    {
        constexpr int T = 1024 / CIN;
        constexpr int RR = SER / T;
        int ci = tid % CIN, s = tid / CIN;
        const float* wp = w2t + (size_t)(s * RR) * CIN + ci;
        float a = 0.f;
        #pragma unroll 4
        for (int r = 0; r < RR; r++) a = fmaf(wp[(size_t)r * CIN], hid[s * RR + r], a);
        part[tid] = a;
    }
    __syncthreads();
    if (tid < CIN) {
        constexpr int T = 1024 / CIN;
        float g = b2[tid];
        #pragma unroll
        for (int s2 = 0; s2 < T; s2++) g += part[s2 * CIN + tid];
        gate[b * CIN + tid] = 1.f / (1.f + __expf(-g));
    }
}

// ======= MFMA 1x1 conv =====================================================
// C^T[n][co] = X'^T[n][ci] x W[co][ci]:  M = n (16/block), N = co, K = ci.
// A-input: staged fp32->bf16 LDS (default), attn-merge (po), or DIRECT bf16
// transposed global buffer (inbf, [b*1728+n][ci]) — no LDS, no barriers.
// Output: fp32 [b][co][n] (out) and/or bf16 side-layouts (obf):
//   obfm=1 (qkv): co<256 -> qk[b*16+co>>4][n][d] (Q scaled); co>=256 -> v[b*8+h][d][n]
//   obfm=2: dense transposed [b*1728+n][co]
template<int CIN, int COUT>
__global__ __launch_bounds__(256) void convm_kernel(
        const float* __restrict__ in, const short* __restrict__ inbf,
        const short* __restrict__ wb,
        const float* __restrict__ biasc,
        const float* __restrict__ segate,
        const float* __restrict__ fstats, const float* __restrict__ fg,
        const float* __restrict__ fb, int fgs,
        const float* __restrict__ ing, const float* __restrict__ inb,
        const float* __restrict__ inres,
        const float* __restrict__ po, const float* __restrict__ pl,
        float* __restrict__ xout,
        const float* resid, float* out,
        short* __restrict__ obf, int obfm,
        float* stats_out, const float* __restrict__ statres, int act) {
    constexpr int XP = CIN + 8;          // bf16 row pitch (16B-multiple rows)
    __shared__ float sc[CIN];
    __shared__ float sh[CIN];
    __shared__ float sa[CIN];
    __shared__ float sbl[CIN];
    __shared__ float hid[128];
    __shared__ __align__(16) short xa[16 * XP];
    int flat = blockIdx.x;
    int b = flat / 108, mt = flat % 108;
    int n0 = mt * 16;
    int tid = threadIdx.x;

    if (!inbf) {
    if (po) {
        // ---- attention-merge staging: X = (sum_js po) / l, ci = h*16+d ----
        if (tid < 128) {
            int hh = tid >> 4, j = tid & 15;
            float l = 0.f;
            #pragma unroll
            for (int js = 0; js < 6; js++)
                l += pl[(size_t)((b * 8 + hh) * 6 + js) * NSP + n0 + j];
            hid[tid] = 1.f / l;
        }
        __syncthreads();
        #pragma unroll
        for (int i = 0; i < CIN / 64; i++) {
            int e = tid + i * 256;
            int ci = e >> 2;
            int jj = (e & 3) * 4;
            int hh = ci >> 4, d = ci & 15;
            float4 acc = {0.f, 0.f, 0.f, 0.f};
            #pragma unroll
            for (int js = 0; js < 6; js++) {
                float4 pv = *(const float4*)(po +
                    ((size_t)((b * 8 + hh) * 6 + js) * 16 + d) * NSP + n0 + jj);
                acc.x += pv.x; acc.y += pv.y; acc.z += pv.z; acc.w += pv.w;
            }
            float4 li = *(const float4*)(hid + hh * 16 + jj);
            xa[(jj + 0) * XP + ci] = f2bf(acc.x * li.x);
            xa[(jj + 1) * XP + ci] = f2bf(acc.y * li.y);
            xa[(jj + 2) * XP + ci] = f2bf(acc.z * li.z);
            xa[(jj + 3) * XP + ci] = f2bf(acc.w * li.w);
        }
        __syncthreads();
    } else {
    // ---- preamble: per-ci scale/shift ----
    if (segate) {
        for (int c = tid; c < CIN; c += 256) {
            sc[c] = segate[b * CIN + c];
            sh[c] = 0.f;
        }
    } else if (ing) {
        for (int c = tid; c < CIN; c += 256) {
            const float* S = fstats + (size_t)(b * CIN + c) * 5;
            float A = S[0], Bq = S[1], Cq = S[2], Dq = S[3], Eq = S[4];
            const float N = (float)NSP;
            float mean = A / N, var = Bq / N - mean * mean;
            float a_ = ing[c] * rsqrtf(var + 1e-5f);
            float b_ = inb[c] - mean * a_;
            sa[c] = a_; sbl[c] = b_;
            sc[c] = a_ * A + b_ * N + Dq;                       // Σ x2
            sh[c] = a_ * a_ * Bq + 2.f * a_ * b_ * A + b_ * b_ * N
                  + 2.f * a_ * Cq + 2.f * b_ * Dq + Eq;         // Σ x2²
        }
        __syncthreads();
        float gS = 0.f, gS2 = 0.f;
        if (tid < CIN) {
            int g0 = (tid / fgs) * fgs;
            for (int k = 0; k < fgs; k++) { gS += sc[g0 + k]; gS2 += sh[g0 + k]; }
        }
        __syncthreads();
        if (tid < CIN) {
            float Ng = fgs * (float)NSP;
            float gm = gS / Ng, gv = gS2 / Ng - gm * gm;
            float s_ = rsqrtf(gv + 1e-5f) * fg[tid];
            sc[tid] = s_;
            sh[tid] = fb[tid] - gm * s_;
        }
    } else if (fstats) {
        for (int c = tid; c < CIN; c += 256) {
            int g0 = c / fgs;
            float S = 0.f, S2 = 0.f;
            for (int k = 0; k < fgs; k++) {
                S  += fstats[(b * CIN + g0 * fgs + k) * 2];
                S2 += fstats[(b * CIN + g0 * fgs + k) * 2 + 1];
            }
            float N = fgs * (float)NSP;
            float mean = S / N, var = S2 / N - mean * mean;
            float s = rsqrtf(var + 1e-5f) * fg[c];
            sc[c] = s;
            sh[c] = fb[c] - mean * s;
        }
    } else {
        for (int c = tid; c < CIN; c += 256) { sc[c] = 1.f; sh[c] = 0.f; }
    }
    __syncthreads();

    // ---- stage X' tile [n=16][ci] bf16 (fp32 fold applied pre-round) ----
    bool dosw = (xout != nullptr) && (blockIdx.y == 0);
    #pragma unroll
    for (int i = 0; i < CIN / 64; i++) {
        int e = tid + i * 256;           // e in [0, 4*CIN)
        int ci = e >> 2;
        int jj = (e & 3) * 4;
        size_t gi = ((size_t)b * CIN + ci) * NSP + n0 + jj;
        float4 v4 = *(const float4*)(in + gi);
        float v0, v1, v2, v3;
        if (ing) {
            float4 rr = *(const float4*)(inres + gi);
            float a_ = sa[ci], b_ = sbl[ci];
            float x0 = fmaf(v4.x, a_, b_) + rr.x;
            float x1 = fmaf(v4.y, a_, b_) + rr.y;
            float x2 = fmaf(v4.z, a_, b_) + rr.z;
            float x3 = fmaf(v4.w, a_, b_) + rr.w;
            if (dosw) {
                float4 o; o.x = x0; o.y = x1; o.z = x2; o.w = x3;
                *(float4*)(xout + gi) = o;
            }
            float s_ = sc[ci], h_ = sh[ci];
            v0 = fmaf(x0, s_, h_); v1 = fmaf(x1, s_, h_);
            v2 = fmaf(x2, s_, h_); v3 = fmaf(x3, s_, h_);
        } else {
            float s_ = sc[ci], h_ = sh[ci];
            v0 = fmaf(v4.x, s_, h_); v1 = fmaf(v4.y, s_, h_);
            v2 = fmaf(v4.z, s_, h_); v3 = fmaf(v4.w, s_, h_);
            if (dosw) {
                float4 o; o.x = v0; o.y = v1; o.z = v2; o.w = v3;
                *(float4*)(xout + gi) = o;
            }
        }
        xa[(jj + 0) * XP + ci] = f2bf(v0);
        xa[(jj + 1) * XP + ci] = f2bf(v1);
        xa[(jj + 2) * XP + ci] = f2bf(v2);
        xa[(jj + 3) * XP + ci] = f2bf(v3);
    }
    __syncthreads();
    }
    }  // !inbf

    // ---- compute: no further barriers ----
    int lane = tid & 63, wv = tid >> 6;
    int col = lane & 15, quad = lane >> 4;
    short8 afr[CIN / 32];
    if (inbf) {
        const short* ar = inbf + ((size_t)b * 1728 + n0 + col) * CIN;
        #pragma unroll
        for (int kc = 0; kc < CIN / 32; kc++)
            afr[kc] = ld8(ar + kc * 32 + quad * 8);
    } else {
        #pragma unroll
        for (int kc = 0; kc < CIN / 32; kc++)
            afr[kc] = ld8(xa + col * XP + kc * 32 + quad * 8);
    }

    int cobase = blockIdx.y * 64 + wv * 16;
    int co = cobase + col;
    const short* wrow = wb + (size_t)co * CIN;
    floatx4 acc = {0.f, 0.f, 0.f, 0.f};
    #pragma unroll
    for (int kc = 0; kc < CIN / 32; kc++) {
        short8 bw = ld8(wrow + kc * 32 + quad * 8);
        acc = __builtin_amdgcn_mfma_f32_16x16x32_bf16(afr[kc], bw, acc, 0, 0, 0);
    }
    float bv = biasc ? biasc[co] : 0.f;
    float r0 = acc[0] + bv, r1 = acc[1] + bv, r2 = acc[2] + bv, r3 = acc[3] + bv;
    if (act == 2) {
        r0 = 0.5f * r0 * (1.f + erff(r0 * 0.70710678118654752f));
        r1 = 0.5f * r1 * (1.f + erff(r1 * 0.70710678118654752f));
        r2 = 0.5f * r2 * (1.f + erff(r2 * 0.70710678118654752f));
        r3 = 0.5f * r3 * (1.f + erff(r3 * 0.70710678118654752f));
    }
    size_t oi = ((size_t)b * COUT + co) * NSP + n0 + quad * 4;
    if (resid) {
        float4 rv = *(const float4*)(resid + oi);
        r0 += rv.x; r1 += rv.y; r2 += rv.z; r3 += rv.w;
    }
    if (obf) {
        if (obfm == 1) {
            if (co < 256) {
                // qk[b*16 + (co>>4)][n][d=co&15], Q (co<128) pre-scaled
                float s_ = (co < 128) ? 0.36067376022224085f : 1.f;
                short* qb = obf + (((size_t)(b * 16 + (co >> 4)) * 1728 + n0 + quad * 4) * 16
                                   + (co & 15));
                qb[0]  = f2bf(r0 * s_);
                qb[16] = f2bf(r1 * s_);
                qb[32] = f2bf(r2 * s_);
                qb[48] = f2bf(r3 * s_);
            } else {
                // v[b*8 + h][d][n] — natural [d][n], 8B contiguous per lane
                short* vb = obf + 884736
                    + ((size_t)(b * 8 + ((co - 256) >> 4)) * 16 + (co & 15)) * 1728
                    + n0 + quad * 4;
                uint2 pv; pv.x = pack2bf(r0, r1); pv.y = pack2bf(r2, r3);
                *(uint2*)vb = pv;
            }
        } else {
            // dense transposed [b*1728+n][co]
            short* hb = obf + ((size_t)b * 1728 + n0 + quad * 4) * COUT + co;
            hb[0]        = f2bf(r0);
            hb[COUT]     = f2bf(r1);
            hb[2 * COUT] = f2bf(r2);
            hb[3 * COUT] = f2bf(r3);
        }
    }
    if (out) {
        float4 ov; ov.x = r0; ov.y = r1; ov.z = r2; ov.w = r3;
        *(float4*)(out + oi) = ov;
    }
    if (stats_out) {
        if (statres) {
            float4 rv = *(const float4*)(statres + oi);
            float s   = (r0 + r1) + (r2 + r3);
            float s2  = (r0 * r0 + r1 * r1) + (r2 * r2 + r3 * r3);
            float sx  = (r0 * rv.x + r1 * rv.y) + (r2 * rv.z + r3 * rv.w);
            float sr  = (rv.x + rv.y) + (rv.z + rv.w);
            float sr2 = (rv.x * rv.x + rv.y * rv.y) + (rv.z * rv.z + rv.w * rv.w);
            s   += __shfl_xor(s,   16, 64); s   += __shfl_xor(s,   32, 64);
            s2  += __shfl_xor(s2,  16, 64); s2  += __shfl_xor(s2,  32, 64);
            sx  += __shfl_xor(sx,  16, 64); sx  += __shfl_xor(sx,  32, 64);
            sr  += __shfl_xor(sr,  16, 64); sr  += __shfl_xor(sr,  32, 64);
            sr2 += __shfl_xor(sr2, 16, 64); sr2 += __shfl_xor(sr2, 32, 64);
            if (lane < 16) {
                float* sp = stats_out + (size_t)(b * COUT + cobase + lane) * 5;
                atomicAdd(sp + 0, s);
                atomicAdd(sp + 1, s2);
                atomicAdd(sp + 2, sx);
                atomicAdd(sp + 3, sr);
                atomicAdd(sp + 4, sr2);
            }
        } else {
            float s  = (r0 + r1) + (r2 + r3);
            float s2 = (r0 * r0 + r1 * r1) + (r2 * r2 + r3 * r3);
            s  += __shfl_xor(s,  16, 64);
            s  += __shfl_xor(s,  32, 64);
            s2 += __shfl_xor(s2, 16, 64);
            s2 += __shfl_xor(s2, 32, 64);
            if (lane < 16) {
                atomicAdd(&stats_out[(b * COUT + cobase + lane) * 2],     s);
                atomicAdd(&stats_out[(b * COUT + cobase + lane) * 2 + 1], s2);
            }
        }
    }
}

// ======= IN+SiLU + depthwise 3x3x3 (halo LDS) + IN+SiLU + SE-squeeze =======
__global__ __launch_bounds__(256) void indw_kernel(
        const float* __restrict__ in,
        const float* __restrict__ g1, const float* __restrict__ b1,
        const float* __restrict__ dw,
        const float* __restrict__ g2, const float* __restrict__ b2,
        float* __restrict__ out, float* __restrict__ se_s, int C) {
    int bc = blockIdx.x;
    int c  = bc % C;
    __shared__ float tile[14 * 14 * 14];   // zero-padded halo volume
    __shared__ float wsh[27];
    const float* ip = in + (size_t)bc * NSP;
    float r[7];
    float s = 0.f, s2 = 0.f;
    for (int i = threadIdx.x; i < 2744; i += 256) tile[i] = 0.f;
    #pragma unroll
    for (int i = 0; i < 7; i++) {
        int n = threadIdx.x + i * 256;
        if (n < NSP) { r[i] = ip[n]; s += r[i]; s2 += r[i] * r[i]; }
        else r[i] = 0.f;
    }
    if (threadIdx.x < 27) wsh[threadIdx.x] = dw[(size_t)c * 27 + threadIdx.x];
    block_reduce2(s, s2);
    float mean = s / NSP, var = s2 / NSP - (s / NSP) * (s / NSP);
    float rstd = rsqrtf(var + 1e-5f);
    float gc = g1[c], bc1 = b1[c];
    #pragma unroll
    for (int i = 0; i < 7; i++) {
        int n = threadIdx.x + i * 256;
        if (n < NSP) {
            int z = n / 144, y = (n / 12) % 12, x = n % 12;
            float v = (r[i] - mean) * rstd * gc + bc1;
            tile[((z + 1) * 14 + y + 1) * 14 + x + 1] = v / (1.f + __expf(-v));
        }
    }
    __syncthreads();
    float d[7];
    #pragma unroll
    for (int i = 0; i < 7; i++) {
        int n = threadIdx.x + i * 256;
        d[i] = 0.f;
        if (n < NSP) {
            int z = n / 144, y = (n / 12) % 12, x = n % 12;
            const float* ctr = tile + ((z + 1) * 14 + y + 1) * 14 + x + 1;
            float acc = 0.f;
            #pragma unroll
            for (int dz = 0; dz < 3; dz++)
                #pragma unroll
                for (int dy = 0; dy < 3; dy++)
                    #pragma unroll
                    for (int dx = 0; dx < 3; dx++)
                        acc = fmaf(wsh[dz * 9 + dy * 3 + dx],
                                   ctr[(dz - 1) * 196 + (dy - 1) * 14 + (dx - 1)], acc);
            d[i] = acc;
        }
    }
    s = 0.f; s2 = 0.f;
    #pragma unroll
    for (int i = 0; i < 7; i++) {
        int n = threadIdx.x + i * 256;
        if (n < NSP) { s += d[i]; s2 += d[i] * d[i]; }
    }
    block_reduce2(s, s2);
    mean = s / NSP; var = s2 / NSP - mean * mean;
    rstd = rsqrtf(var + 1e-5f);
    float gc2 = g2[c], bc2 = b2[c];
    float ssum = 0.f;
    float* op = out + (size_t)bc * NSP;
    #pragma unroll
    for (int i = 0; i < 7; i++) {
        int n = threadIdx.x + i * 256;
        if (n < NSP) {
            float v = (d[i] - mean) * rstd * gc2 + bc2;
            v = v / (1.f + __expf(-v));
            op[n] = v;
            ssum += v;
        }
    }
    float dummy = 0.f;
    block_reduce2(ssum, dummy);
    if (threadIdx.x == 0) se_s[bc] = ssum / NSP;
}

// ======= MFMA flash attention, j-split 6, S^T, ZERO staging ================
// Q/K from qkbf [b*16 + h][n][16] bf16 (Q pre-scaled, h>=8 is K);
// V from vbf [b*8 + h][d][n] bf16. Fragments loaded directly from global;
// LDS = per-wave P-exchange only (4.6 KB); no block barriers at all.
#define APT 36
#define JCH 288
__global__ __launch_bounds__(256) void attn_split_kernel(
        const short* __restrict__ qkbf, const short* __restrict__ vbf,
        float* __restrict__ po, float* __restrict__ pl) {
    __shared__ __align__(16) short pt[4][16 * APT]; // per wave [q][j]
    int bh = blockIdx.x;
    int b = bh >> 3, h = bh & 7;
    int js = blockIdx.z;
    int j0 = js * JCH;
    int wave = threadIdx.x >> 6, lane = threadIdx.x & 63;
    int m = lane & 15, quad = lane >> 4;
    int q0 = (blockIdx.y * 4 + wave) * 16;
    short* ptw = pt[wave];
    const short* qrow  = qkbf + ((size_t)(b * 16 + h) * 1728 + q0 + m) * 16;
    const short* kbase = qkbf + ((size_t)(b * 16 + 8 + h) * 1728 + j0) * 16;
    const short* vbase = vbf + ((size_t)(b * 8 + h) * 16) * 1728 + j0;
    short8 qa;
    #pragma unroll
    for (int i = 0; i < 8; i++) qa[i] = 0;
    if (quad < 2) qa = ld8(qrow + quad * 8);
    floatx4 o = {0.f, 0.f, 0.f, 0.f};
    float ls = 0.f;
    #pragma unroll
    for (int s = 0; s < 9; s++) {
        int jl = s * 32;
        short8 ak0, ak1;
        #pragma unroll
        for (int i = 0; i < 8; i++) { ak0[i] = 0; ak1[i] = 0; }
        if (quad < 2) {
            ak0 = ld8(kbase + (jl + m) * 16 + quad * 8);
            ak1 = ld8(kbase + (jl + 16 + m) * 16 + quad * 8);
        }
        floatx4 s0 = {0.f, 0.f, 0.f, 0.f}, s1 = {0.f, 0.f, 0.f, 0.f};
        s0 = __builtin_amdgcn_mfma_f32_16x16x32_bf16(ak0, qa, s0, 0, 0, 0);
        s1 = __builtin_amdgcn_mfma_f32_16x16x32_bf16(ak1, qa, s1, 0, 0, 0);
        float p0r0 = fexp2(s0[0]), p0r1 = fexp2(s0[1]), p0r2 = fexp2(s0[2]), p0r3 = fexp2(s0[3]);
        float p1r0 = fexp2(s1[0]), p1r1 = fexp2(s1[1]), p1r2 = fexp2(s1[2]), p1r3 = fexp2(s1[3]);
        ls += (p0r0 + p0r1) + (p0r2 + p0r3) + (p1r0 + p1r1) + (p1r2 + p1r3);
        uint2 w0, w1;
        w0.x = pack2bf(p0r0, p0r1); w0.y = pack2bf(p0r2, p0r3);
        w1.x = pack2bf(p1r0, p1r1); w1.y = pack2bf(p1r2, p1r3);
        *(uint2*)(ptw + m * APT + quad * 4)      = w0;
        *(uint2*)(ptw + m * APT + 16 + quad * 4) = w1;
        short8 av = ld8(vbase + (size_t)m * 1728 + jl + quad * 8);
        short8 pb = ld8(ptw + m * APT + quad * 8);
        o = __builtin_amdgcn_mfma_f32_16x16x32_bf16(av, pb, o, 0, 0, 0);
    }
    ls += __shfl_xor(ls, 16, 64);
    ls += __shfl_xor(ls, 32, 64);
    size_t pbase = ((size_t)(bh * 6 + js) * 16) * NSP;
    #pragma unroll
    for (int r = 0; r < 4; r++)
        po[pbase + (size_t)(quad * 4 + r) * NSP + q0 + m] = o[r];
    if (quad == 0) pl[(size_t)(bh * 6 + js) * NSP + q0 + m] = ls;
}

// ======= shuffle attn final: inline gates + gnstats + gating + shuffle =====
__global__ void sfinal_kernel(const float* __restrict__ X,
                              const float* __restrict__ st,
                              const float* __restrict__ cw1,
                              const float* __restrict__ cw2,
                              const float* __restrict__ gng,
                              const float* __restrict__ gnb,
                              const float* __restrict__ sw,
                              float* __restrict__ out) {
    int bg = blockIdx.x;
    int b = bg >> 2, g = bg & 3;
    __shared__ float swl[256];
    for (int i = threadIdx.x; i < 256; i += 64) swl[i] = sw[i];
    __syncthreads();
    float pooled[16];
    #pragma unroll
    for (int j = 0; j < 16; j++)
        pooled[j] = st[(b * 128 + g * 32 + j) * 2] * (1.f / NSP);
    float hid[4];
    #pragma unroll
    for (int r = 0; r < 4; r++) {
        float a = 0.f;
        #pragma unroll
        for (int j = 0; j < 16; j++) a = fmaf(cw1[r * 16 + j], pooled[j], a);
        hid[r] = a / (1.f + __expf(-a));
    }
    float gate[16];
    #pragma unroll
    for (int j = 0; j < 16; j++) {
        float a = 0.f;
        #pragma unroll
        for (int r = 0; r < 4; r++) a = fmaf(cw2[j * 4 + r], hid[r], a);
        gate[j] = 1.f / (1.f + __expf(-a));
    }
    float gmean[2], grstd[2];
    #pragma unroll
    for (int t = 0; t < 2; t++) {
        float S = 0.f, S2 = 0.f;
        #pragma unroll
        for (int k = 0; k < 8; k++) {
            int c = g * 32 + 16 + t * 8 + k;
            S  += st[(b * 128 + c) * 2];
            S2 += st[(b * 128 + c) * 2 + 1];
        }
        float N = 8.f * NSP;
        gmean[t] = S / N;
        grstd[t] = rsqrtf(S2 / N - gmean[t] * gmean[t] + 1e-5f);
    }
    int n = blockIdx.y * 64 + threadIdx.x;
    const float* xb = X + (size_t)b * 128 * NSP;
    #pragma unroll
    for (int j = 0; j < 16; j++) {
        float v = xb[(size_t)(g * 32 + j) * NSP + n] * gate[j];
        int k = g * 16 + j;
        int cp = (k % 32) * 4 + (k / 32);
        out[((size_t)b * 128 + cp) * NSP + n] = v;
    }
    float sgn[16];
    #pragma unroll
    for (int j = 0; j < 16; j++) {
        int grp = j >> 3;
        float xv = xb[(size_t)(g * 32 + 16 + j) * NSP + n];
        sgn[j] = (xv - gmean[grp]) * grstd[grp] * gng[j] + gnb[j];
    }
    #pragma unroll
    for (int j = 0; j < 16; j++) {
        float a = 0.f;
        #pragma unroll
        for (int jp = 0; jp < 16; jp++) a = fmaf(swl[j * 16 + jp], sgn[jp], a);
        float v = (1.f / (1.f + __expf(-a))) * xb[(size_t)(g * 32 + 16 + j) * NSP + n];
        int k = 64 + g * 16 + j;
        int cp = (k % 32) * 4 + (k / 32);
        out[((size_t)b * 128 + cp) * NSP + n] = v;
    }
}

// ===========================================================================
extern "C" void kernel_launch(void* const* d_in, const int* in_sizes, int n_in,
                              void* d_out, int out_size, void* d_ws, size_t ws_size,
                              hipStream_t stream) {
    const float* x     = (const float*)d_in[0];
    const float* m1_ew = (const float*)d_in[1];
    const float* m1_g1 = (const float*)d_in[2];
    const float* m1_b1 = (const float*)d_in[3];
    const float* m1_dw = (const float*)d_in[4];
    const float* m1_g2 = (const float*)d_in[5];
    const float* m1_b2 = (const float*)d_in[6];
    const float* m1_sw1= (const float*)d_in[7];
    const float* m1_sb1= (const float*)d_in[8];
    const float* m1_sw2= (const float*)d_in[9];
    const float* m1_sb2= (const float*)d_in[10];
    const float* m1_pw = (const float*)d_in[11];
    const float* m1_g3 = (const float*)d_in[12];
    const float* m1_b3 = (const float*)d_in[13];
    const float* m2_ew = (const float*)d_in[14];
    const float* m2_g1 = (const float*)d_in[15];
    const float* m2_b1 = (const float*)d_in[16];
    const float* m2_dw = (const float*)d_in[17];
    const float* m2_g2 = (const float*)d_in[18];
    const float* m2_b2 = (const float*)d_in[19];
    const float* m2_sw1= (const float*)d_in[20];
    const float* m2_sb1= (const float*)d_in[21];
    const float* m2_sw2= (const float*)d_in[22];
    const float* m2_sb2= (const float*)d_in[23];
    const float* m2_pw = (const float*)d_in[24];
    const float* m2_g3 = (const float*)d_in[25];
    const float* m2_b3 = (const float*)d_in[26];
    const float* t_n1g = (const float*)d_in[27];
    const float* t_n1b = (const float*)d_in[28];
    const float* t_qkv = (const float*)d_in[29];
    const float* t_pw  = (const float*)d_in[30];
    const float* t_pb  = (const float*)d_in[31];
    const float* t_n2g = (const float*)d_in[32];
    const float* t_n2b = (const float*)d_in[33];
    const float* t_mw1 = (const float*)d_in[34];
    const float* t_mb1 = (const float*)d_in[35];
    const float* t_mw2 = (const float*)d_in[36];
    const float* t_mb2 = (const float*)d_in[37];
    const float* s_cw1 = (const float*)d_in[38];
    const float* s_cw2 = (const float*)d_in[39];
    const float* s_gng = (const float*)d_in[40];
    const float* s_gnb = (const float*)d_in[41];
    const float* s_sw  = (const float*)d_in[42];

    float* out = (float*)d_out;

    float* ws = (float*)d_ws;
    float* bufA   = ws;                                 // 2*512*NSP (attn po spills into bufB; mlp1 hbf)
    float* bufB   = bufA + (size_t)BB * 512 * NSP;      // 2*512*NSP
    float* bufX   = bufB + (size_t)BB * 512 * NSP;      // 2*128*NSP (x1)
    float* bufY   = bufX + (size_t)BB * 128 * NSP;      // 2*128*NSP (raw proj out)
    float* bufQKV = bufY + (size_t)BB * 128 * NSP;      // 2*384*NSP region -> qkbf/vbf bf16
    float* pl     = bufQKV + (size_t)BB * 384 * NSP;    // 16*6*NSP
    float* small  = pl + (size_t)16 * 6 * NSP;
    float* se_s   = small;            // 1024 (pooled means from indw)
    float* st1    = small + 1024;     // 512, m1proj raw stats (atomic, zeroed)
    float* st3    = small + 1536;     // 512, attn-proj stats (atomic, zeroed)
    float* st4    = small + 2048;     // 512, mlp2 stats (atomic, zeroed)
    float* st2    = small + 2560;     // 1280, m2proj 5-term stats (atomic, zeroed)
    float* gate1  = small + 4096;     // 512, m1 SE gate
    float* gate2  = small + 4608;     // 1024, m2 SE gate
    short* wbf    = (short*)(small + 8192);   // 376832 bf16 weights
    float* tsw    = small + 196608;   // 163840 fp32 transposed SE weights
    float* T_M1SW1 = tsw;             // [256][64]
    float* T_M1SW2 = tsw + 16384;     // [64][256]
    float* T_M2SW1 = tsw + 32768;     // [512][128]
    float* T_M2SW2 = tsw + 98304;     // [128][512]
    float* bufX2  = tsw + 163840;     // 2*128*NSP (x2 materialized)
    float* po     = bufA;             // attn partials 16*6*16*NSP
    short* qkbf   = (short*)bufQKV;   // [b*16+h][1728][16] Q(h<8,scaled)+K(h>=8); vbf at +884736
    short* hbf    = (short*)bufA;     // mlp1 out bf16 transposed [b*1728+n][512]

    // bf16 weight offsets (elements) — must match prep_kernel's table
    short* W_M1EW = wbf + 0;
    short* W_M1PW = wbf + 16384;
    short* W_M2EW = wbf + 49152;
    short* W_M2PW = wbf + 114688;
    short* W_QKV  = wbf + 180224;
    short* W_TPW  = wbf + 229376;
    short* W_MW1  = wbf + 245760;
    short* W_MW2  = wbf + 311296;

    dim3 blk(256);

    prep_kernel<<<528, blk, 0, stream>>>(
        m1_ew, m1_pw, m2_ew, m2_pw, t_qkv, t_pw, t_mw1, t_mw2, wbf, st1,
        m1_sw1, m1_sw2, m2_sw1, m2_sw2, tsw);

    // ---------------- MBConv1: 64 -> 256 -> 128 ----------------
    convm_kernel<64, 256><<<dim3(BB * 108, 4), blk, 0, stream>>>(
        x, nullptr, W_M1EW, nullptr, nullptr,
        nullptr, nullptr, nullptr, 0,
        nullptr, nullptr, nullptr,
        nullptr, nullptr, nullptr,
        nullptr, bufA, nullptr, 0, nullptr, nullptr, 0);
    indw_kernel<<<BB * 256, blk, 0, stream>>>(bufA, m1_g1, m1_b1, m1_dw, m1_g2, m1_b2, bufB, se_s, 256);
    segate_kernel<256, 64><<<BB, dim3(1024), 0, stream>>>(
        se_s, T_M1SW1, m1_sb1, T_M1SW2, m1_sb2, gate1);
    convm_kernel<256, 128><<<dim3(BB * 108, 2), blk, 0, stream>>>(   // proj + SE gate
        bufB, nullptr, W_M1PW, nullptr, gate1,
        nullptr, nullptr, nullptr, 0,
        nullptr, nullptr, nullptr,
        nullptr, nullptr, nullptr,
        nullptr, bufY, nullptr, 0, st1, nullptr, 0);

    // ---------------- MBConv2: 128 -> 512 -> 128 (+res) ----------------
    convm_kernel<128, 512><<<dim3(BB * 108, 8), blk, 0, stream>>>(   // expand + IN-fold, side-write x1
        bufY, nullptr, W_M2EW, nullptr, nullptr,
        st1, m1_g3, m1_b3, 1,
        nullptr, nullptr, nullptr,
        nullptr, nullptr, bufX,
        nullptr, bufA, nullptr, 0, nullptr, nullptr, 0);
    indw_kernel<<<BB * 512, blk, 0, stream>>>(bufA, m2_g1, m2_b1, m2_dw, m2_g2, m2_b2, bufB, se_s, 512);
    segate_kernel<512, 128><<<BB, dim3(1024), 0, stream>>>(
        se_s, T_M2SW1, m2_sb1, T_M2SW2, m2_sb2, gate2);
    convm_kernel<512, 128><<<dim3(BB * 108, 2), blk, 0, stream>>>(   // proj + SE gate + 5-term stats
        bufB, nullptr, W_M2PW, nullptr, gate2,
        nullptr, nullptr, nullptr, 0,
        nullptr, nullptr, nullptr,
        nullptr, nullptr, nullptr,
        nullptr, bufY, nullptr, 0, st2, bufX, 0);

    // ---------------- Transformer ----------------
    convm_kernel<128, 384><<<dim3(BB * 108, 6), blk, 0, stream>>>(   // qkv: fold + bf16 Q/K/V layouts
        bufY, nullptr, W_QKV, nullptr, nullptr,
        st2, t_n1g, t_n1b, 4,
        m2_g3, m2_b3, bufX,
        nullptr, nullptr, bufX2,
        nullptr, nullptr, qkbf, 1, nullptr, nullptr, 0);
    attn_split_kernel<<<dim3(16, 27, 6), blk, 0, stream>>>(qkbf, qkbf + 884736, po, pl);
    convm_kernel<128, 128><<<dim3(BB * 108, 2), blk, 0, stream>>>(   // attn merge + proj + resid
        nullptr, nullptr, W_TPW, t_pb, nullptr,
        nullptr, nullptr, nullptr, 0,
        nullptr, nullptr, nullptr,
        po, pl, nullptr,
        bufX2, bufX2, nullptr, 0, st3, nullptr, 0);
    convm_kernel<128, 512><<<dim3(BB * 108, 8), blk, 0, stream>>>(   // mlp1 + gnorm2-fold + GELU -> bf16T
        bufX2, nullptr, W_MW1, t_mb1, nullptr,
        st3, t_n2g, t_n2b, 4,
        nullptr, nullptr, nullptr,
        nullptr, nullptr, nullptr,
        nullptr, nullptr, hbf, 2, nullptr, nullptr, 2);
    convm_kernel<512, 128><<<dim3(BB * 108, 2), blk, 0, stream>>>(   // mlp2: direct bf16 A + resid
        nullptr, hbf, W_MW2, t_mb2, nullptr,
        nullptr, nullptr, nullptr, 0,
        nullptr, nullptr, nullptr,
        nullptr, nullptr, nullptr,
        bufX2, bufX2, nullptr, 0, st4, nullptr, 0);

    // ---------------- Shuffle attention ----------------
    sfinal_kernel<<<dim3(BB * 4, 27), dim3(64), 0, stream>>>(
        bufX2, st4, s_cw1, s_cw2, s_gng, s_gnb, s_sw, out);
}